// Round 6
// baseline (461.516 us; speedup 1.0000x reference)
//
#include <hip/hip_runtime.h>
#include <hip/hip_bf16.h>
#include <math.h>

// MoE FFN: T=2048 tokens, H=1024, F=2816, E=8, top-2, SwiGLU + aux loss.
// R4: double-buffered LDS + 2-phase prefetch in both GEMMs. (473 us)
// R5: counted-vmcnt graft w/ 3 bufs + dynamic idx -> REGRESSION (reverted).
// R6: gemm1 128x64 tile: occupancy up, time flat -> occupancy theory dead.
// R7: gemm1 2-buffer counted-vmcnt {vmcnt(4); bar; compute; bar; stage},
//     prep fusion (10 -> 6 launches). 454 us; top kernel now prep (124 us,
//     HBM 29%, VALU 8.5%, occ 51% -> latency/duty-cycle-bound).
// R8: transpose blocks process 4 k-tiles with register-prefetch pipelining
//     (loads of tile t+1 in flight under phase2 of tile t). Blocks 16896
//     -> 4224. Layouts/banking identical to verified R7 code. GEMMs
//     untouched.

#define T_TOK 2048
#define HID   1024
#define DFF   2816
#define NE    8
#define ROWS  4096   // T_TOK * TOP_K

typedef unsigned short u16;
typedef __attribute__((ext_vector_type(8))) short bf16x8;
typedef __attribute__((ext_vector_type(4))) float f32x4;

// ---- workspace layout (bytes) ----
#define OFF_CNT    0                       // int[8]
#define OFF_IMP    64                      // float[8]
#define OFF_OFFS   128                     // int[8]
#define OFF_TOPKI  256                     // int[4096]
#define OFF_TOPKP  (OFF_TOPKI + 16384)     // float[4096]
#define OFF_BTOK   (OFF_TOPKP + 16384)     // int[8][2048]
#define OFF_EPOS   (OFF_BTOK + 65536)      // int[4096] (expert<<11 | pos)
#define OFF_XB     (OFF_EPOS + 65536)      // bf16[2048][1024]
#define OFF_W1T    (OFF_XB + 4194304)      // bf16[8][2816][1024]  (transposed)
#define OFF_W3T    (OFF_W1T + 46137344)
#define OFF_W2T    (OFF_W3T + 46137344)    // bf16[8][1024][2816]  (transposed)
#define OFF_ACT    (OFF_W2T + 46137344)    // bf16[4096][2816]
#define WS_NEEDED  (OFF_ACT + 23068672)    // ~158.2 MiB
// ybuf (f32[4096][1024] = 16.8 MB) overlays OFF_W1T: w1t is dead after gemm1.

// prep_kernel block ranges (4-tile transpose blocks)
#define PB_W1   1408                 // 44 nx * 4 kgrp * 8 e
#define PB_W3   2816
#define PB_W2   4224                 // + 16 nx * 11 kgrp * 8 e
#define PB_CVT  6272                 // + 2048
#define PB_GATE 6784                 // + 512 (4 tokens/block)

__device__ __forceinline__ u16 f2bf(float f) {
    unsigned u = __float_as_uint(f);
    u = (u + 0x7fffu + ((u >> 16) & 1u)) >> 16;   // RNE
    return (u16)u;
}

// async global->LDS, 16B per lane; LDS dest wave-uniform base (+lane*16 implicit)
__device__ __forceinline__ void glds16(const void* g, void* l) {
    __builtin_amdgcn_global_load_lds(
        (const __attribute__((address_space(1))) unsigned int*)g,
        (__attribute__((address_space(3))) unsigned int*)l, 16, 0, 0);
}

// ---- fp32 [K][N] -> bf16 [N][K], nt k-tiles of 64x64 per block, pipelined ----
// Loads of tile t+1 are issued (into regs) before phase2 of tile t, so
// ~16 KB of reads stays in flight under the LDS-transpose/cvt/store phase.
__device__ __forceinline__ void transpose4_body(const float* ip, u16* op, int K, int N,
                                                int n0, int k0base, int nt, int tid,
                                                float tile[64][65]) {
    float4 rA[4];
    int row_r = tid >> 4;          // 0..15 (load-phase row within 16-row group)
    int v = (tid & 15) * 4;        // load-phase col (floats)
    int colg = (tid & 7) * 8;      // phase2 k-offset
    int nn = tid >> 3;             // phase2 n (0..31), +p*32

    {   // preload tile 0
        const float* bp = ip + (size_t)k0base * N + n0;
#pragma unroll
        for (int p = 0; p < 4; ++p)
            rA[p] = *(const float4*)(bp + (size_t)(p * 16 + row_r) * N + v);
    }
    for (int t = 0; t < nt; ++t) {
        int k0 = k0base + t * 64;
        __syncthreads();                       // prior phase2 LDS reads done
#pragma unroll
        for (int p = 0; p < 4; ++p) {
            int row = p * 16 + row_r;
            tile[row][v] = rA[p].x; tile[row][v + 1] = rA[p].y;
            tile[row][v + 2] = rA[p].z; tile[row][v + 3] = rA[p].w;
        }
        __syncthreads();
        if (t + 1 < nt) {                      // prefetch next tile -> regs
            const float* bp = ip + (size_t)(k0 + 64) * N + n0;
#pragma unroll
            for (int p = 0; p < 4; ++p)
                rA[p] = *(const float4*)(bp + (size_t)(p * 16 + row_r) * N + v);
        }
#pragma unroll
        for (int p = 0; p < 2; ++p) {          // phase2: LDS cols -> bf16 out
            int n = p * 32 + nn;
            u16 o[8];
#pragma unroll
            for (int j = 0; j < 8; ++j) o[j] = f2bf(tile[colg + j][n]);
            *(bf16x8*)(op + (size_t)(n0 + n) * K + k0 + colg) = *(bf16x8*)o;
        }
    }
}

// ---- fused prep: w1/w3/w2 transpose + cvt_x + gating, one launch ----
__global__ void prep_kernel(const float* __restrict__ x, u16* __restrict__ xb,
                            const float* __restrict__ w1, u16* __restrict__ w1t,
                            const float* __restrict__ w3, u16* __restrict__ w3t,
                            const float* __restrict__ w2, u16* __restrict__ w2t,
                            const float* __restrict__ gw, int* __restrict__ topki,
                            float* __restrict__ topkp, float* __restrict__ imp) {
    __shared__ float tile[64][65];
    __shared__ float s_imp[NE];
    int id = blockIdx.x, tid = threadIdx.x;

    if (id < PB_W3) {                       // w1 / w3: K=HID, N=DFF, 4 kgrps
        const float* in = (id < PB_W1) ? w1 : w3;
        u16* out = (id < PB_W1) ? w1t : w3t;
        int id1 = (id < PB_W1) ? id : id - PB_W1;
        int bx = id1 % 44, byz = id1 / 44;  // byz 0..31
        int by = byz & 3, bz = byz >> 2;    // by: k-group (256 k each)
        transpose4_body(in + (size_t)bz * HID * DFF, out + (size_t)bz * HID * DFF,
                        HID, DFF, bx * 64, by * 256, 4, tid, tile);
    } else if (id < PB_W2) {                // w2: K=DFF, N=HID, 11 kgrps
        int id2 = id - PB_W3;
        int bx = id2 & 15, byz = id2 >> 4;  // byz 0..87
        int by = byz % 11, bz = byz / 11;
        transpose4_body(w2 + (size_t)bz * DFF * HID, w2t + (size_t)bz * DFF * HID,
                        DFF, HID, bx * 64, by * 256, 4, tid, tile);
    } else if (id < PB_CVT) {               // fp32 -> bf16 x convert
        int i = (id - PB_W2) * 256 + tid;
        float4 v = ((const float4*)x)[i];
        union { u16 s[4]; unsigned long long q; } o;
        o.s[0] = f2bf(v.x); o.s[1] = f2bf(v.y); o.s[2] = f2bf(v.z); o.s[3] = f2bf(v.w);
        ((unsigned long long*)xb)[i] = o.q;
    } else {                                // gating: 4 tokens per block
        if (tid < NE) s_imp[tid] = 0.f;
        __syncthreads();
        int lane = tid & 63;
        int t = (id - PB_CVT) * 4 + (tid >> 6);
        float a[NE];
#pragma unroll
        for (int e = 0; e < NE; ++e) a[e] = 0.f;
#pragma unroll
        for (int c = 0; c < 16; ++c) {
            float xv = x[(size_t)t * HID + c * 64 + lane];
#pragma unroll
            for (int e = 0; e < NE; ++e) a[e] += xv * gw[e * HID + c * 64 + lane];
        }
#pragma unroll
        for (int e = 0; e < NE; ++e) {
#pragma unroll
            for (int off = 32; off > 0; off >>= 1) a[e] += __shfl_xor(a[e], off, 64);
        }
        if (lane == 0) {
            float v0 = -1e30f, v1 = -1e30f; int e0 = 0, e1 = 0;
#pragma unroll
            for (int e = 0; e < NE; ++e) {
                if (a[e] > v0) { v1 = v0; e1 = e0; v0 = a[e]; e0 = e; }
                else if (a[e] > v1) { v1 = a[e]; e1 = e; }
            }
            float p0 = 1.f / (1.f + expf(v1 - v0));
            topki[2 * t] = e0; topki[2 * t + 1] = e1;
            topkp[2 * t] = p0; topkp[2 * t + 1] = 1.f - p0;
            float s = 0.f, pe[NE];
#pragma unroll
            for (int e = 0; e < NE; ++e) { pe[e] = expf(a[e] - v0); s += pe[e]; }
            float inv = 1.f / s;
#pragma unroll
            for (int e = 0; e < NE; ++e) atomicAdd(&s_imp[e], pe[e] * inv);
        }
        __syncthreads();
        if (tid < NE) atomicAdd(&imp[tid], s_imp[tid]);
    }
}

// ---- bucket append + epos record ----
__global__ void compact_kernel(const int* __restrict__ topki,
                               int* __restrict__ cnt, int* __restrict__ btok,
                               int* __restrict__ epos) {
    int idx = blockIdx.x * 256 + threadIdx.x;
    int e = topki[idx];
    int pos = atomicAdd(&cnt[e], 1);
    btok[e * T_TOK + pos] = idx >> 1;
    epos[idx] = (e << 11) | pos;
}

// ---- offsets + aux loss ----
__global__ void finalize_kernel(const int* __restrict__ cnt, const float* __restrict__ imp,
                                int* __restrict__ offs, float* __restrict__ aux_out) {
    if (threadIdx.x == 0) {
        int off = 0; float s = 0.f;
        for (int e = 0; e < NE; ++e) {
            offs[e] = off; off += cnt[e];
            s += ((float)cnt[e] / (4096.f + 1e-9f)) * (imp[e] / 2048.f);
        }
        aux_out[0] = fminf(s * 8.f * 0.01f, 1.f);
    }
}

// ---- GEMM1: act = silu(X@W1) * (X@W3), 128x64 tile, BK=32 ----
// Counted-vmcnt double-buffer: per step {vmcnt(4); bar; compute(p); bar;
// STAGE(p, k+2)}. NO vmcnt(0) drain in the main loop.
__global__ __launch_bounds__(256, 3)
void gemm1_kernel(const u16* __restrict__ xb, const u16* __restrict__ w1t,
                  const u16* __restrict__ w3t, u16* __restrict__ act,
                  const int* __restrict__ btok, const int* __restrict__ cnt,
                  const int* __restrict__ offs) {
    int e = blockIdx.z;
    int n_e = cnt[e];
    int m0 = blockIdx.y * 128;
    if (m0 >= n_e) return;
    int nn0 = blockIdx.x * 64;
    int base = offs[e];

    // [2 buffers]: A 128x32 (8 KB/buf), B1/B3 64x32 (4 KB/buf each) = 32 KB
    __shared__ __align__(16) u16 As[2 * 128 * 32];
    __shared__ __align__(16) u16 B1s[2 * 64 * 32];
    __shared__ __align__(16) u16 B3s[2 * 64 * 32];

    int tid = threadIdx.x, lane = tid & 63, wv = tid >> 6;
    int wm = (wv >> 1) * 64, wn = (wv & 1) * 32;   // wave tile 64x32
    int l15 = lane & 15, quad = lane >> 4;

    int row0 = tid >> 2, row1 = 64 + row0;
    int q = (tid & 3) ^ ((tid >> 3) & 3);    // swizzled global 16B-quad
    int sub = q * 8;
    int t0 = (m0 + row0 < n_e) ? btok[e * T_TOK + m0 + row0] : 0;
    int t1 = (m0 + row1 < n_e) ? btok[e * T_TOK + m0 + row1] : 0;
    const u16* ga0 = xb + (size_t)t0 * HID + sub;
    const u16* ga1 = xb + (size_t)t1 * HID + sub;
    const u16* g1 = w1t + ((size_t)e * DFF + nn0 + row0) * HID + sub;
    const u16* g3 = w3t + ((size_t)e * DFF + nn0 + row0) * HID + sub;
    int wa0 = wv * 512;          // (wv*64 rows)*8 : A rows 0-63 half
    int wa1 = 2048 + wv * 512;   // rows 64-127 half
    int wb  = wv * 512;          // B rows

    f32x4 acc1[4][2] = {}, acc3[4][2] = {};

    // stage one BK=32 tile (4 glds16 per thread) into buffer BUF
#define STG1(BUF, K0) do {                                                     \
        int nA_ = (BUF) * 4096, nB_ = (BUF) * 2048;                            \
        glds16(ga0 + (K0), As + nA_ + wa0); glds16(ga1 + (K0), As + nA_ + wa1);\
        glds16(g1 + (K0), B1s + nB_ + wb);  glds16(g3 + (K0), B3s + nB_ + wb); \
    } while (0)

    STG1(0, 0);      // tile 0 -> buf 0 (4 loads in flight)
    STG1(1, 32);     // tile 1 -> buf 1 (8 in flight)

    int p = 0;
    for (int k0 = 0; k0 < HID; k0 += 32) {
        // retire only tile-k's 4 loads; tile-k+1's stay in flight
        if (k0 + 32 < HID) asm volatile("s_waitcnt vmcnt(4)" ::: "memory");
        else               asm volatile("s_waitcnt vmcnt(0)" ::: "memory");
        __builtin_amdgcn_s_barrier();            // all waves: buffer p ready
        asm volatile("" ::: "memory");
        const u16* Ab  = As  + p * 4096;
        const u16* B1b = B1s + p * 2048;
        const u16* B3b = B3s + p * 2048;
        bf16x8 af[4];
#pragma unroll
        for (int i = 0; i < 4; ++i) {
            int R = wm + i * 16 + l15;
            af[i] = *(const bf16x8*)&Ab[R * 32 + (quad ^ ((R >> 1) & 3)) * 8];
        }
#pragma unroll
        for (int j = 0; j < 2; ++j) {
            int R = wn + j * 16 + l15;
            int so = R * 32 + (quad ^ ((R >> 1) & 3)) * 8;
            bf16x8 b1 = *(const bf16x8*)&B1b[so];
            bf16x8 b3 = *(const bf16x8*)&B3b[so];
#pragma unroll
            for (int i = 0; i < 4; ++i) {
                acc1[i][j] = __builtin_amdgcn_mfma_f32_16x16x32_bf16(af[i], b1, acc1[i][j], 0, 0, 0);
                acc3[i][j] = __builtin_amdgcn_mfma_f32_16x16x32_bf16(af[i], b3, acc3[i][j], 0, 0, 0);
            }
        }
        asm volatile("" ::: "memory");
        __builtin_amdgcn_s_barrier();            // all waves done reading buf p
        asm volatile("" ::: "memory");
        if (k0 + 64 < HID) STG1(p, k0 + 64);     // reuse just-freed buffer p
        p ^= 1;
    }
#undef STG1
#pragma unroll
    for (int i = 0; i < 4; ++i) {
#pragma unroll
        for (int r = 0; r < 4; ++r) {
            int m = m0 + wm + i * 16 + quad * 4 + r;
            if (m < n_e) {
#pragma unroll
                for (int j = 0; j < 2; ++j) {
                    float h1 = acc1[i][j][r], h3 = acc3[i][j][r];
                    float v = h1 / (1.f + expf(-h1)) * h3;   // silu(h1)*h3
                    act[(size_t)(base + m) * DFF + nn0 + wn + j * 16 + l15] = f2bf(v);
                }
            }
        }
    }
}

// ---- GEMM2: ybuf[row] = act[row] @ W2, 64x128 tile, BK=64, double-buffered ----
// (R4 version verbatim: BK=64 as two 32-col sub-regions, 48 KB LDS, 3 blk/CU)
__global__ __launch_bounds__(256, 3)
void gemm2_kernel(const u16* __restrict__ act, const u16* __restrict__ w2t,
                  float* __restrict__ ybuf, const int* __restrict__ cnt,
                  const int* __restrict__ offs) {
    int e = blockIdx.z;
    int n_e = cnt[e];
    int m0 = blockIdx.y * 64;
    if (m0 >= n_e) return;
    int nn0 = blockIdx.x * 128;
    int base = offs[e];

    // As: [2 buf][2 khalf][64 rows][32]  = 16 KB
    // Bs: [2 buf][2 khalf][128 rows][32] = 32 KB
    __shared__ __align__(16) u16 As[2 * 2 * 64 * 32];
    __shared__ __align__(16) u16 Bs[2 * 2 * 128 * 32];

    int tid = threadIdx.x, lane = tid & 63, wv = tid >> 6;
    int wn = wv * 32;
    int l15 = lane & 15, quad = lane >> 4;

    int row0 = tid >> 2;
    int q = (tid & 3) ^ ((tid >> 3) & 3);
    int sub = q * 8;
    int ra = (m0 + row0 < n_e) ? (base + m0 + row0) : base;
    const u16* ga0 = act + (size_t)ra * DFF + sub;
    const u16* gb0 = w2t + ((size_t)e * HID + nn0 + row0) * DFF + sub;
    const u16* gb1 = w2t + ((size_t)e * HID + nn0 + 64 + row0) * DFF + sub;
    int wb = (wv * 64) * 8;   // u16 index of wave's 1 KB slice (16 rows)

    f32x4 acc[4][2] = {};

    // stage one BK=64 tile (two 32-col halves) into buffer p
#define STAGE2(P, K0)                                                          \
    do {                                                                       \
        _Pragma("unroll")                                                      \
        for (int h = 0; h < 2; ++h) {                                          \
            int ab = (P) * 4096 + h * 2048;                                    \
            int bb = (P) * 8192 + h * 4096;                                    \
            glds16(ga0 + (K0) + h * 32, As + ab + wb);                         \
            glds16(gb0 + (K0) + h * 32, Bs + bb + wb);                         \
            glds16(gb1 + (K0) + h * 32, Bs + bb + 2048 + wb);                  \
        }                                                                      \
    } while (0)

    STAGE2(0, 0);
    __syncthreads();

    int p = 0;
    for (int k0 = 0; k0 < DFF; k0 += 64) {
        if (k0 + 64 < DFF) STAGE2(p ^ 1, k0 + 64);
#pragma unroll
        for (int kk = 0; kk < 2; ++kk) {
            const u16* Ab = As + p * 4096 + kk * 2048;
            const u16* Bb = Bs + p * 8192 + kk * 4096;
            bf16x8 af[4];
#pragma unroll
            for (int i = 0; i < 4; ++i) {
                int R = i * 16 + l15;
                af[i] = *(const bf16x8*)&Ab[R * 32 + (quad ^ ((R >> 1) & 3)) * 8];
            }
#pragma unroll
            for (int j = 0; j < 2; ++j) {
                int R = wn + j * 16 + l15;
                bf16x8 bf = *(const bf16x8*)&Bb[R * 32 + (quad ^ ((R >> 1) & 3)) * 8];
#pragma unroll
                for (int i = 0; i < 4; ++i)
                    acc[i][j] = __builtin_amdgcn_mfma_f32_16x16x32_bf16(af[i], bf, acc[i][j], 0, 0, 0);
            }
        }
        __syncthreads();
        p ^= 1;
    }
#undef STAGE2
#pragma unroll
    for (int i = 0; i < 4; ++i) {
#pragma unroll
        for (int r = 0; r < 4; ++r) {
            int m = m0 + i * 16 + quad * 4 + r;
            if (m < n_e) {
#pragma unroll
                for (int j = 0; j < 2; ++j)
                    ybuf[(size_t)(base + m) * HID + nn0 + wn + j * 16 + l15] = acc[i][j][r];
            }
        }
    }
}

// ---- combine: out[t] = p0*ybuf[r0] + p1*ybuf[r1] ----
__global__ void combine_kernel(const float* __restrict__ ybuf, const int* __restrict__ epos,
                               const float* __restrict__ topkp, const int* __restrict__ offs,
                               float* __restrict__ out) {
    int t = blockIdx.x;
    int c = threadIdx.x * 4;
    int ep0 = epos[2 * t], ep1 = epos[2 * t + 1];
    int r0 = offs[ep0 >> 11] + (ep0 & 2047);
    int r1 = offs[ep1 >> 11] + (ep1 & 2047);
    float p0 = topkp[2 * t], p1 = topkp[2 * t + 1];
    float4 a = *(const float4*)&ybuf[(size_t)r0 * HID + c];
    float4 b = *(const float4*)&ybuf[(size_t)r1 * HID + c];
    float4 o;
    o.x = p0 * a.x + p1 * b.x; o.y = p0 * a.y + p1 * b.y;
    o.z = p0 * a.z + p1 * b.z; o.w = p0 * a.w + p1 * b.w;
    *(float4*)&out[(size_t)t * HID + c] = o;
}

extern "C" void kernel_launch(void* const* d_in, const int* in_sizes, int n_in,
                              void* d_out, int out_size, void* d_ws, size_t ws_size,
                              hipStream_t stream) {
    if (ws_size < (size_t)WS_NEEDED) return;  // clean failure signature (0xAA output)

    const float* x  = (const float*)d_in[0];
    const float* gw = (const float*)d_in[1];
    const float* w1 = (const float*)d_in[2];
    const float* w3 = (const float*)d_in[3];
    const float* w2 = (const float*)d_in[4];
    float* out = (float*)d_out;

    char* ws = (char*)d_ws;
    int*   cnt   = (int*)(ws + OFF_CNT);
    float* imp   = (float*)(ws + OFF_IMP);
    int*   offs  = (int*)(ws + OFF_OFFS);
    int*   topki = (int*)(ws + OFF_TOPKI);
    float* topkp = (float*)(ws + OFF_TOPKP);
    int*   btok  = (int*)(ws + OFF_BTOK);
    int*   epos  = (int*)(ws + OFF_EPOS);
    u16*   xb    = (u16*)(ws + OFF_XB);
    u16*   w1t   = (u16*)(ws + OFF_W1T);
    u16*   w3t   = (u16*)(ws + OFF_W3T);
    u16*   w2t   = (u16*)(ws + OFF_W2T);
    u16*   actb  = (u16*)(ws + OFF_ACT);
    float* ybuf  = (float*)(ws + OFF_W1T);   // overlay: w1t dead after gemm1

    hipMemsetAsync(ws, 0, 256, stream);

    prep_kernel<<<PB_GATE, 256, 0, stream>>>(x, xb, w1, w1t, w3, w3t, w2, w2t,
                                             gw, topki, topkp, imp);
    compact_kernel<<<ROWS / 256, 256, 0, stream>>>(topki, cnt, btok, epos);
    finalize_kernel<<<1, 64, 0, stream>>>(cnt, imp, offs, out + (size_t)T_TOK * HID);

    gemm1_kernel<<<dim3(DFF / 64, T_TOK / 128, NE), 256, 0, stream>>>(
        xb, w1t, w3t, actb, btok, cnt, offs);
    gemm2_kernel<<<dim3(HID / 128, T_TOK / 64, NE), 256, 0, stream>>>(
        actb, w2t, ybuf, cnt, offs);
    combine_kernel<<<T_TOK, 256, 0, stream>>>(ybuf, epos, topkp, offs, out);
}

// Round 8
// 449.419 us; speedup vs baseline: 1.0269x; 1.0269x over previous
//
#include <hip/hip_runtime.h>
#include <hip/hip_bf16.h>
#include <math.h>

// MoE FFN: T=2048 tokens, H=1024, F=2816, E=8, top-2, SwiGLU + aux loss.
// R4: double-buffered LDS + 2-phase prefetch in both GEMMs. (473 us)
// R5: counted-vmcnt graft w/ 3 bufs + dynamic idx -> REGRESSION (reverted).
// R6: gemm1 128x64 tile: occupancy up, time flat -> occupancy theory dead.
// R7: gemm1 2-buffer counted-vmcnt, prep fusion. 454 us; prep now top
//     (124 us, HBM 36% of achievable, latency-bound).
// R8: 4-tile intra-block pipelining -> NULL (129 us): in-flight depth
//     unchanged (4 float4/wave). Little's law: need ~22KB/CU in flight,
//     have ~8KB -> 36% of BW ceiling, matches measurement.
// R9: transpose tile 64k x 128n: 8 outstanding float4/thread (2x depth),
//     512B read runs (2x coalescing), LDS [64][129] odd-pad (bank-free
//     column reads). Everything else byte-identical to R7/R8.
// R9b: resubmit verbatim (infra failure, no data; audit found nothing
//      hang-capable — same flake signature as R4, which passed on retry).

#define T_TOK 2048
#define HID   1024
#define DFF   2816
#define NE    8
#define ROWS  4096   // T_TOK * TOP_K

typedef unsigned short u16;
typedef __attribute__((ext_vector_type(8))) short bf16x8;
typedef __attribute__((ext_vector_type(4))) float f32x4;

// ---- workspace layout (bytes) ----
#define OFF_CNT    0                       // int[8]
#define OFF_IMP    64                      // float[8]
#define OFF_OFFS   128                     // int[8]
#define OFF_TOPKI  256                     // int[4096]
#define OFF_TOPKP  (OFF_TOPKI + 16384)     // float[4096]
#define OFF_BTOK   (OFF_TOPKP + 16384)     // int[8][2048]
#define OFF_EPOS   (OFF_BTOK + 65536)      // int[4096] (expert<<11 | pos)
#define OFF_XB     (OFF_EPOS + 65536)      // bf16[2048][1024]
#define OFF_W1T    (OFF_XB + 4194304)      // bf16[8][2816][1024]  (transposed)
#define OFF_W3T    (OFF_W1T + 46137344)
#define OFF_W2T    (OFF_W3T + 46137344)    // bf16[8][1024][2816]  (transposed)
#define OFF_ACT    (OFF_W2T + 46137344)    // bf16[4096][2816]
#define WS_NEEDED  (OFF_ACT + 23068672)    // ~158.2 MiB
// ybuf (f32[4096][1024] = 16.8 MB) overlays OFF_W1T: w1t is dead after gemm1.

// prep_kernel block ranges (64k x 128n transpose tiles)
#define PB_W1   2816                 // 22 nx * 16 kx * 8 e
#define PB_W3   5632
#define PB_W2   8448                 // + 8 nx * 44 kx * 8 e
#define PB_CVT  10496                // + 2048
#define PB_GATE 11008                // + 512 (4 tokens/block)

__device__ __forceinline__ u16 f2bf(float f) {
    unsigned u = __float_as_uint(f);
    u = (u + 0x7fffu + ((u >> 16) & 1u)) >> 16;   // RNE
    return (u16)u;
}

// async global->LDS, 16B per lane; LDS dest wave-uniform base (+lane*16 implicit)
__device__ __forceinline__ void glds16(const void* g, void* l) {
    __builtin_amdgcn_global_load_lds(
        (const __attribute__((address_space(1))) unsigned int*)g,
        (__attribute__((address_space(3))) unsigned int*)l, 16, 0, 0);
}

// ---- fp32 [K][N] -> bf16 [N][K], one 64k x 128n tile per block ----
// Phase1: 8 outstanding float4/thread, 512B contiguous runs per k-row.
// LDS [64][129]: odd pad -> column read bank = (k + n) mod 32, 2-way free.
// Phase2: 4 passes x 32 n-rows, each thread 8 scalar LDS reads + 16B store.
__device__ __forceinline__ void transpose128_body(const float* ip, u16* op,
                                                  int K, int N, int n0, int k0,
                                                  int tid, float tile[64][129]) {
    float4 rA[8];
    int lr = tid >> 5;            // 0..7 (row within 8-row group)
    int lc = (tid & 31) * 4;      // 0..124 (float col)
#pragma unroll
    for (int p = 0; p < 8; ++p)
        rA[p] = *(const float4*)(ip + (size_t)(k0 + p * 8 + lr) * N + n0 + lc);
#pragma unroll
    for (int p = 0; p < 8; ++p) {
        int row = p * 8 + lr;
        tile[row][lc] = rA[p].x; tile[row][lc + 1] = rA[p].y;
        tile[row][lc + 2] = rA[p].z; tile[row][lc + 3] = rA[p].w;
    }
    __syncthreads();
    int colg = (tid & 7) * 8;     // k offset 0..56
    int nn = tid >> 3;            // 0..31
#pragma unroll
    for (int pass = 0; pass < 4; ++pass) {
        int n = pass * 32 + nn;
        u16 o[8];
#pragma unroll
        for (int j = 0; j < 8; ++j) o[j] = f2bf(tile[colg + j][n]);
        *(bf16x8*)(op + (size_t)(n0 + n) * K + k0 + colg) = *(bf16x8*)o;
    }
}

// ---- fused prep: w1/w3/w2 transpose + cvt_x + gating, one launch ----
__global__ void prep_kernel(const float* __restrict__ x, u16* __restrict__ xb,
                            const float* __restrict__ w1, u16* __restrict__ w1t,
                            const float* __restrict__ w3, u16* __restrict__ w3t,
                            const float* __restrict__ w2, u16* __restrict__ w2t,
                            const float* __restrict__ gw, int* __restrict__ topki,
                            float* __restrict__ topkp, float* __restrict__ imp) {
    __shared__ float tile[64][129];
    __shared__ float s_imp[NE];
    int id = blockIdx.x, tid = threadIdx.x;

    if (id < PB_W3) {                       // w1 / w3: K=HID, N=DFF
        const float* in = (id < PB_W1) ? w1 : w3;
        u16* out = (id < PB_W1) ? w1t : w3t;
        int id1 = (id < PB_W1) ? id : id - PB_W1;
        int bx = id1 % 22, byz = id1 / 22;  // byz 0..127
        int by = byz & 15, bz = byz >> 4;
        transpose128_body(in + (size_t)bz * HID * DFF, out + (size_t)bz * HID * DFF,
                          HID, DFF, bx * 128, by * 64, tid, tile);
    } else if (id < PB_W2) {                // w2: K=DFF, N=HID
        int id2 = id - PB_W3;
        int bx = id2 & 7, byz = id2 >> 3;   // byz 0..351
        int by = byz % 44, bz = byz / 44;
        transpose128_body(w2 + (size_t)bz * DFF * HID, w2t + (size_t)bz * DFF * HID,
                          DFF, HID, bx * 128, by * 64, tid, tile);
    } else if (id < PB_CVT) {               // fp32 -> bf16 x convert
        int i = (id - PB_W2) * 256 + tid;
        float4 v = ((const float4*)x)[i];
        union { u16 s[4]; unsigned long long q; } o;
        o.s[0] = f2bf(v.x); o.s[1] = f2bf(v.y); o.s[2] = f2bf(v.z); o.s[3] = f2bf(v.w);
        ((unsigned long long*)xb)[i] = o.q;
    } else {                                // gating: 4 tokens per block
        if (tid < NE) s_imp[tid] = 0.f;
        __syncthreads();
        int lane = tid & 63;
        int t = (id - PB_CVT) * 4 + (tid >> 6);
        float a[NE];
#pragma unroll
        for (int e = 0; e < NE; ++e) a[e] = 0.f;
#pragma unroll
        for (int c = 0; c < 16; ++c) {
            float xv = x[(size_t)t * HID + c * 64 + lane];
#pragma unroll
            for (int e = 0; e < NE; ++e) a[e] += xv * gw[e * HID + c * 64 + lane];
        }
#pragma unroll
        for (int e = 0; e < NE; ++e) {
#pragma unroll
            for (int off = 32; off > 0; off >>= 1) a[e] += __shfl_xor(a[e], off, 64);
        }
        if (lane == 0) {
            float v0 = -1e30f, v1 = -1e30f; int e0 = 0, e1 = 0;
#pragma unroll
            for (int e = 0; e < NE; ++e) {
                if (a[e] > v0) { v1 = v0; e1 = e0; v0 = a[e]; e0 = e; }
                else if (a[e] > v1) { v1 = a[e]; e1 = e; }
            }
            float p0 = 1.f / (1.f + expf(v1 - v0));
            topki[2 * t] = e0; topki[2 * t + 1] = e1;
            topkp[2 * t] = p0; topkp[2 * t + 1] = 1.f - p0;
            float s = 0.f, pe[NE];
#pragma unroll
            for (int e = 0; e < NE; ++e) { pe[e] = expf(a[e] - v0); s += pe[e]; }
            float inv = 1.f / s;
#pragma unroll
            for (int e = 0; e < NE; ++e) atomicAdd(&s_imp[e], pe[e] * inv);
        }
        __syncthreads();
        if (tid < NE) atomicAdd(&imp[tid], s_imp[tid]);
    }
}

// ---- bucket append + epos record ----
__global__ void compact_kernel(const int* __restrict__ topki,
                               int* __restrict__ cnt, int* __restrict__ btok,
                               int* __restrict__ epos) {
    int idx = blockIdx.x * 256 + threadIdx.x;
    int e = topki[idx];
    int pos = atomicAdd(&cnt[e], 1);
    btok[e * T_TOK + pos] = idx >> 1;
    epos[idx] = (e << 11) | pos;
}

// ---- offsets + aux loss ----
__global__ void finalize_kernel(const int* __restrict__ cnt, const float* __restrict__ imp,
                                int* __restrict__ offs, float* __restrict__ aux_out) {
    if (threadIdx.x == 0) {
        int off = 0; float s = 0.f;
        for (int e = 0; e < NE; ++e) {
            offs[e] = off; off += cnt[e];
            s += ((float)cnt[e] / (4096.f + 1e-9f)) * (imp[e] / 2048.f);
        }
        aux_out[0] = fminf(s * 8.f * 0.01f, 1.f);
    }
}

// ---- GEMM1: act = silu(X@W1) * (X@W3), 128x64 tile, BK=32 ----
// Counted-vmcnt double-buffer: per step {vmcnt(4); bar; compute(p); bar;
// STAGE(p, k+2)}. NO vmcnt(0) drain in the main loop.
__global__ __launch_bounds__(256, 3)
void gemm1_kernel(const u16* __restrict__ xb, const u16* __restrict__ w1t,
                  const u16* __restrict__ w3t, u16* __restrict__ act,
                  const int* __restrict__ btok, const int* __restrict__ cnt,
                  const int* __restrict__ offs) {
    int e = blockIdx.z;
    int n_e = cnt[e];
    int m0 = blockIdx.y * 128;
    if (m0 >= n_e) return;
    int nn0 = blockIdx.x * 64;
    int base = offs[e];

    // [2 buffers]: A 128x32 (8 KB/buf), B1/B3 64x32 (4 KB/buf each) = 32 KB
    __shared__ __align__(16) u16 As[2 * 128 * 32];
    __shared__ __align__(16) u16 B1s[2 * 64 * 32];
    __shared__ __align__(16) u16 B3s[2 * 64 * 32];

    int tid = threadIdx.x, lane = tid & 63, wv = tid >> 6;
    int wm = (wv >> 1) * 64, wn = (wv & 1) * 32;   // wave tile 64x32
    int l15 = lane & 15, quad = lane >> 4;

    int row0 = tid >> 2, row1 = 64 + row0;
    int q = (tid & 3) ^ ((tid >> 3) & 3);    // swizzled global 16B-quad
    int sub = q * 8;
    int t0 = (m0 + row0 < n_e) ? btok[e * T_TOK + m0 + row0] : 0;
    int t1 = (m0 + row1 < n_e) ? btok[e * T_TOK + m0 + row1] : 0;
    const u16* ga0 = xb + (size_t)t0 * HID + sub;
    const u16* ga1 = xb + (size_t)t1 * HID + sub;
    const u16* g1 = w1t + ((size_t)e * DFF + nn0 + row0) * HID + sub;
    const u16* g3 = w3t + ((size_t)e * DFF + nn0 + row0) * HID + sub;
    int wa0 = wv * 512;          // (wv*64 rows)*8 : A rows 0-63 half
    int wa1 = 2048 + wv * 512;   // rows 64-127 half
    int wb  = wv * 512;          // B rows

    f32x4 acc1[4][2] = {}, acc3[4][2] = {};

    // stage one BK=32 tile (4 glds16 per thread) into buffer BUF
#define STG1(BUF, K0) do {                                                     \
        int nA_ = (BUF) * 4096, nB_ = (BUF) * 2048;                            \
        glds16(ga0 + (K0), As + nA_ + wa0); glds16(ga1 + (K0), As + nA_ + wa1);\
        glds16(g1 + (K0), B1s + nB_ + wb);  glds16(g3 + (K0), B3s + nB_ + wb); \
    } while (0)

    STG1(0, 0);      // tile 0 -> buf 0 (4 loads in flight)
    STG1(1, 32);     // tile 1 -> buf 1 (8 in flight)

    int p = 0;
    for (int k0 = 0; k0 < HID; k0 += 32) {
        // retire only tile-k's 4 loads; tile-k+1's stay in flight
        if (k0 + 32 < HID) asm volatile("s_waitcnt vmcnt(4)" ::: "memory");
        else               asm volatile("s_waitcnt vmcnt(0)" ::: "memory");
        __builtin_amdgcn_s_barrier();            // all waves: buffer p ready
        asm volatile("" ::: "memory");
        const u16* Ab  = As  + p * 4096;
        const u16* B1b = B1s + p * 2048;
        const u16* B3b = B3s + p * 2048;
        bf16x8 af[4];
#pragma unroll
        for (int i = 0; i < 4; ++i) {
            int R = wm + i * 16 + l15;
            af[i] = *(const bf16x8*)&Ab[R * 32 + (quad ^ ((R >> 1) & 3)) * 8];
        }
#pragma unroll
        for (int j = 0; j < 2; ++j) {
            int R = wn + j * 16 + l15;
            int so = R * 32 + (quad ^ ((R >> 1) & 3)) * 8;
            bf16x8 b1 = *(const bf16x8*)&B1b[so];
            bf16x8 b3 = *(const bf16x8*)&B3b[so];
#pragma unroll
            for (int i = 0; i < 4; ++i) {
                acc1[i][j] = __builtin_amdgcn_mfma_f32_16x16x32_bf16(af[i], b1, acc1[i][j], 0, 0, 0);
                acc3[i][j] = __builtin_amdgcn_mfma_f32_16x16x32_bf16(af[i], b3, acc3[i][j], 0, 0, 0);
            }
        }
        asm volatile("" ::: "memory");
        __builtin_amdgcn_s_barrier();            // all waves done reading buf p
        asm volatile("" ::: "memory");
        if (k0 + 64 < HID) STG1(p, k0 + 64);     // reuse just-freed buffer p
        p ^= 1;
    }
#undef STG1
#pragma unroll
    for (int i = 0; i < 4; ++i) {
#pragma unroll
        for (int r = 0; r < 4; ++r) {
            int m = m0 + wm + i * 16 + quad * 4 + r;
            if (m < n_e) {
#pragma unroll
                for (int j = 0; j < 2; ++j) {
                    float h1 = acc1[i][j][r], h3 = acc3[i][j][r];
                    float v = h1 / (1.f + expf(-h1)) * h3;   // silu(h1)*h3
                    act[(size_t)(base + m) * DFF + nn0 + wn + j * 16 + l15] = f2bf(v);
                }
            }
        }
    }
}

// ---- GEMM2: ybuf[row] = act[row] @ W2, 64x128 tile, BK=64, double-buffered ----
// (R4 version verbatim: BK=64 as two 32-col sub-regions, 48 KB LDS, 3 blk/CU)
__global__ __launch_bounds__(256, 3)
void gemm2_kernel(const u16* __restrict__ act, const u16* __restrict__ w2t,
                  float* __restrict__ ybuf, const int* __restrict__ cnt,
                  const int* __restrict__ offs) {
    int e = blockIdx.z;
    int n_e = cnt[e];
    int m0 = blockIdx.y * 64;
    if (m0 >= n_e) return;
    int nn0 = blockIdx.x * 128;
    int base = offs[e];

    // As: [2 buf][2 khalf][64 rows][32]  = 16 KB
    // Bs: [2 buf][2 khalf][128 rows][32] = 32 KB
    __shared__ __align__(16) u16 As[2 * 2 * 64 * 32];
    __shared__ __align__(16) u16 Bs[2 * 2 * 128 * 32];

    int tid = threadIdx.x, lane = tid & 63, wv = tid >> 6;
    int wn = wv * 32;
    int l15 = lane & 15, quad = lane >> 4;

    int row0 = tid >> 2;
    int q = (tid & 3) ^ ((tid >> 3) & 3);
    int sub = q * 8;
    int ra = (m0 + row0 < n_e) ? (base + m0 + row0) : base;
    const u16* ga0 = act + (size_t)ra * DFF + sub;
    const u16* gb0 = w2t + ((size_t)e * HID + nn0 + row0) * DFF + sub;
    const u16* gb1 = w2t + ((size_t)e * HID + nn0 + 64 + row0) * DFF + sub;
    int wb = (wv * 64) * 8;   // u16 index of wave's 1 KB slice (16 rows)

    f32x4 acc[4][2] = {};

    // stage one BK=64 tile (two 32-col halves) into buffer p
#define STAGE2(P, K0)                                                          \
    do {                                                                       \
        _Pragma("unroll")                                                      \
        for (int h = 0; h < 2; ++h) {                                          \
            int ab = (P) * 4096 + h * 2048;                                    \
            int bb = (P) * 8192 + h * 4096;                                    \
            glds16(ga0 + (K0) + h * 32, As + ab + wb);                         \
            glds16(gb0 + (K0) + h * 32, Bs + bb + wb);                         \
            glds16(gb1 + (K0) + h * 32, Bs + bb + 2048 + wb);                  \
        }                                                                      \
    } while (0)

    STAGE2(0, 0);
    __syncthreads();

    int p = 0;
    for (int k0 = 0; k0 < DFF; k0 += 64) {
        if (k0 + 64 < DFF) STAGE2(p ^ 1, k0 + 64);
#pragma unroll
        for (int kk = 0; kk < 2; ++kk) {
            const u16* Ab = As + p * 4096 + kk * 2048;
            const u16* Bb = Bs + p * 8192 + kk * 4096;
            bf16x8 af[4];
#pragma unroll
            for (int i = 0; i < 4; ++i) {
                int R = i * 16 + l15;
                af[i] = *(const bf16x8*)&Ab[R * 32 + (quad ^ ((R >> 1) & 3)) * 8];
            }
#pragma unroll
            for (int j = 0; j < 2; ++j) {
                int R = wn + j * 16 + l15;
                bf16x8 bf = *(const bf16x8*)&Bb[R * 32 + (quad ^ ((R >> 1) & 3)) * 8];
#pragma unroll
                for (int i = 0; i < 4; ++i)
                    acc[i][j] = __builtin_amdgcn_mfma_f32_16x16x32_bf16(af[i], bf, acc[i][j], 0, 0, 0);
            }
        }
        __syncthreads();
        p ^= 1;
    }
#undef STAGE2
#pragma unroll
    for (int i = 0; i < 4; ++i) {
#pragma unroll
        for (int r = 0; r < 4; ++r) {
            int m = m0 + i * 16 + quad * 4 + r;
            if (m < n_e) {
#pragma unroll
                for (int j = 0; j < 2; ++j)
                    ybuf[(size_t)(base + m) * HID + nn0 + wn + j * 16 + l15] = acc[i][j][r];
            }
        }
    }
}

// ---- combine: out[t] = p0*ybuf[r0] + p1*ybuf[r1] ----
__global__ void combine_kernel(const float* __restrict__ ybuf, const int* __restrict__ epos,
                               const float* __restrict__ topkp, const int* __restrict__ offs,
                               float* __restrict__ out) {
    int t = blockIdx.x;
    int c = threadIdx.x * 4;
    int ep0 = epos[2 * t], ep1 = epos[2 * t + 1];
    int r0 = offs[ep0 >> 11] + (ep0 & 2047);
    int r1 = offs[ep1 >> 11] + (ep1 & 2047);
    float p0 = topkp[2 * t], p1 = topkp[2 * t + 1];
    float4 a = *(const float4*)&ybuf[(size_t)r0 * HID + c];
    float4 b = *(const float4*)&ybuf[(size_t)r1 * HID + c];
    float4 o;
    o.x = p0 * a.x + p1 * b.x; o.y = p0 * a.y + p1 * b.y;
    o.z = p0 * a.z + p1 * b.z; o.w = p0 * a.w + p1 * b.w;
    *(float4*)&out[(size_t)t * HID + c] = o;
}

extern "C" void kernel_launch(void* const* d_in, const int* in_sizes, int n_in,
                              void* d_out, int out_size, void* d_ws, size_t ws_size,
                              hipStream_t stream) {
    if (ws_size < (size_t)WS_NEEDED) return;  // clean failure signature (0xAA output)

    const float* x  = (const float*)d_in[0];
    const float* gw = (const float*)d_in[1];
    const float* w1 = (const float*)d_in[2];
    const float* w3 = (const float*)d_in[3];
    const float* w2 = (const float*)d_in[4];
    float* out = (float*)d_out;

    char* ws = (char*)d_ws;
    int*   cnt   = (int*)(ws + OFF_CNT);
    float* imp   = (float*)(ws + OFF_IMP);
    int*   offs  = (int*)(ws + OFF_OFFS);
    int*   topki = (int*)(ws + OFF_TOPKI);
    float* topkp = (float*)(ws + OFF_TOPKP);
    int*   btok  = (int*)(ws + OFF_BTOK);
    int*   epos  = (int*)(ws + OFF_EPOS);
    u16*   xb    = (u16*)(ws + OFF_XB);
    u16*   w1t   = (u16*)(ws + OFF_W1T);
    u16*   w3t   = (u16*)(ws + OFF_W3T);
    u16*   w2t   = (u16*)(ws + OFF_W2T);
    u16*   actb  = (u16*)(ws + OFF_ACT);
    float* ybuf  = (float*)(ws + OFF_W1T);   // overlay: w1t dead after gemm1

    hipMemsetAsync(ws, 0, 256, stream);

    prep_kernel<<<PB_GATE, 256, 0, stream>>>(x, xb, w1, w1t, w3, w3t, w2, w2t,
                                             gw, topki, topkp, imp);
    compact_kernel<<<ROWS / 256, 256, 0, stream>>>(topki, cnt, btok, epos);
    finalize_kernel<<<1, 64, 0, stream>>>(cnt, imp, offs, out + (size_t)T_TOK * HID);

    gemm1_kernel<<<dim3(DFF / 64, T_TOK / 128, NE), 256, 0, stream>>>(
        xb, w1t, w3t, actb, btok, cnt, offs);
    gemm2_kernel<<<dim3(HID / 128, T_TOK / 64, NE), 256, 0, stream>>>(
        actb, w2t, ybuf, cnt, offs);
    combine_kernel<<<T_TOK, 256, 0, stream>>>(ybuf, epos, topkp, offs, out);
}